// Round 11
// baseline (126.130 us; speedup 1.0000x reference)
//
#include <hip/hip_runtime.h>
#include <hip/hip_bf16.h>

#define BS 4096
#define D 256
#define NROW 8192      // 2*BS
#define INV_T 2.0f

typedef short short8 __attribute__((ext_vector_type(8)));
typedef float f32x4 __attribute__((ext_vector_type(4)));

__device__ __forceinline__ unsigned short f2b(float x) {
    __hip_bfloat16 h = __float2bfloat16(x);
    return *reinterpret_cast<unsigned short*>(&h);
}
__device__ __forceinline__ float b2f(unsigned short b) {
    unsigned int u = ((unsigned int)b) << 16;
    return __uint_as_float(u);
}

// K1: normalize rows of zi/zj -> bf16 W [8192][256]; zero rowsum + accum(3).
__global__ __launch_bounds__(256) void k_norm(const float* __restrict__ zi,
                                              const float* __restrict__ zj,
                                              unsigned short* __restrict__ W,
                                              float* __restrict__ rowsum,
                                              float* __restrict__ accum) {
    const int gt   = blockIdx.x * 256 + threadIdx.x;
    const int wave = gt >> 6;
    const int lane = threadIdx.x & 63;

    const float* src = (wave < BS) ? (zi + (size_t)wave * D)
                                   : (zj + (size_t)(wave - BS) * D);
    float4 v = reinterpret_cast<const float4*>(src)[lane];
    float ss = v.x * v.x + v.y * v.y + v.z * v.z + v.w * v.w;
#pragma unroll
    for (int m = 1; m < 64; m <<= 1) ss += __shfl_xor(ss, m, 64);
    float inv = rsqrtf(ss);

    ushort4 o;
    o.x = f2b(v.x * inv);
    o.y = f2b(v.y * inv);
    o.z = f2b(v.z * inv);
    o.w = f2b(v.w * inv);
    reinterpret_cast<ushort4*>(W + (size_t)wave * D)[lane] = o;

    if (gt < NROW) rowsum[gt] = 0.0f;
    if (gt < 3)    accum[gt]  = 0.0f;   // [0]=lse, [1]=pos, [2]=done ctr
}

// K2: upper-triangle tiles of G = 2*W@W^T, 128x128 tile, K=256 in 4 steps.
// 8 waves/block (512 thr): wave w -> rows [(w>>2)*64, +64), cols [(w&3)*32, +32).
// Same XOR-swizzled single-buffer LDS + 2-barrier loop as the verified round-9
// kernel (0 bank conflicts) — only the wave decomposition changed (4 -> 8
// lighter waves) to raise resident-wave occupancy in this latency-bound,
// skinny-K regime. Off-diag blocks add both row- and col-sums (symmetry).
__global__ __launch_bounds__(512, 4) void k_gemm(const unsigned short* __restrict__ W,
                                                 float* __restrict__ rowsum) {
    __shared__ unsigned short lA[128 * 64];
    __shared__ unsigned short lB[128 * 64];

    const int tid  = threadIdx.x;
    const int lane = tid & 63;
    const int w    = tid >> 6;      // wave 0..7
    const int wr   = w >> 2;        // 0..1 (64-row half)
    const int wc   = w & 3;         // 0..3 (32-col quarter)

    // triangular decode: t -> (bi,bj), 0 <= bi <= bj < 64
    const int t = blockIdx.x;
    const int u = 2079 - t;
    int ri = (int)((sqrtf(8.0f * (float)u + 1.0f) - 1.0f) * 0.5f);
    while ((ri + 1) * (ri + 2) / 2 <= u) ++ri;
    while (ri * (ri + 1) / 2 > u) --ri;
    const int bi = 63 - ri;
    const int bj = 63 - (u - ri * (ri + 1) / 2);
    const int rowBase = bi * 128;
    const int colBase = bj * 128;
    const bool isDiag = (bi == bj);

    f32x4 acc[4][2] = {};

    // staging: lane l stages phys chunk (row l>>3, chunk l&7) holding logical
    // chunk (l&7)^(row&7)  (swizzle involution applied on the global source)
    const int srcColElems = (((lane & 7) ^ ((lane >> 3) & 7)) * 8);
    const int rowInSeg = (lane >> 3);

    for (int kk = 0; kk < 4; ++kk) {
        const int kBase = kk * 64;
        __syncthreads();   // previous compute done before overwrite
#pragma unroll
        for (int c = 0; c < 2; ++c) {
            const int seg = c * 8 + w;                 // 0..15
            const int row = seg * 8 + rowInSeg;
            const unsigned short* gA = W + (size_t)(rowBase + row) * D + kBase + srcColElems;
            const unsigned short* gB = W + (size_t)(colBase + row) * D + kBase + srcColElems;
            __builtin_amdgcn_global_load_lds(
                (const __attribute__((address_space(1))) void*)gA,
                (__attribute__((address_space(3))) void*)(lA + seg * 512), 16, 0, 0);
            __builtin_amdgcn_global_load_lds(
                (const __attribute__((address_space(1))) void*)gB,
                (__attribute__((address_space(3))) void*)(lB + seg * 512), 16, 0, 0);
        }
        __syncthreads();   // staging complete (vmcnt drained by compiler)

#pragma unroll
        for (int ks = 0; ks < 2; ++ks) {
            short8 a[4], b[2];
            const int swz = lane & 7;
            const int logChunk = ks * 4 + (lane >> 4);
#pragma unroll
            for (int mi = 0; mi < 4; ++mi) {
                const int r = wr * 64 + mi * 16 + (lane & 15);
                a[mi] = *reinterpret_cast<const short8*>(lA + r * 64 + ((logChunk ^ swz) * 8));
            }
#pragma unroll
            for (int ni = 0; ni < 2; ++ni) {
                const int r = wc * 32 + ni * 16 + (lane & 15);
                b[ni] = *reinterpret_cast<const short8*>(lB + r * 64 + ((logChunk ^ swz) * 8));
            }
#pragma unroll
            for (int mi = 0; mi < 4; ++mi)
#pragma unroll
                for (int ni = 0; ni < 2; ++ni)
                    acc[mi][ni] = __builtin_amdgcn_mfma_f32_16x16x32_bf16(
                        a[mi], b[ni], acc[mi][ni], 0, 0, 0);
        }
    }

    // Epilogue. C/D layout (16x16x32): col = lane&15, row = (lane>>4)*4 + reg.
    float colacc[2] = {0.f, 0.f};
#pragma unroll
    for (int mi = 0; mi < 4; ++mi) {
#pragma unroll
        for (int j = 0; j < 4; ++j) {
            const int gr = rowBase + wr * 64 + mi * 16 + (lane >> 4) * 4 + j;
            float s = 0.0f;
#pragma unroll
            for (int ni = 0; ni < 2; ++ni) {
                float e;
                if (isDiag) {
                    const int gc = colBase + wc * 32 + ni * 16 + (lane & 15);
                    e = (gr == gc) ? 0.0f : __expf(acc[mi][ni][j] * INV_T);
                } else {
                    e = __expf(acc[mi][ni][j] * INV_T);
                }
                s += e;
                colacc[ni] += e;
            }
            s += __shfl_xor(s, 1, 64);
            s += __shfl_xor(s, 2, 64);
            s += __shfl_xor(s, 4, 64);
            s += __shfl_xor(s, 8, 64);
            if ((lane & 15) == 0) atomicAdd(&rowsum[gr], s);
        }
    }
    if (!isDiag) {   // symmetric contribution: this tile is also tile (bj,bi)
#pragma unroll
        for (int ni = 0; ni < 2; ++ni) {
            float cs = colacc[ni];
            cs += __shfl_xor(cs, 16, 64);
            cs += __shfl_xor(cs, 32, 64);
            if ((lane >> 4) == 0)
                atomicAdd(&rowsum[colBase + wc * 32 + ni * 16 + lane], cs);
        }
    }
}

// K3: lse_sum = sum(log(rowsum)); pos_sum = sum_i 2*dot(u_i,v_i);
// last finished block writes the final loss.
__global__ __launch_bounds__(256) void k_finalize(const unsigned short* __restrict__ W,
                                                  const float* __restrict__ rowsum,
                                                  float* __restrict__ accum,
                                                  float* __restrict__ out) {
    const int tid  = blockIdx.x * 256 + threadIdx.x;  // 32 blocks -> 8192 threads
    const int lane = threadIdx.x & 63;

    float l = logf(rowsum[tid]);
#pragma unroll
    for (int m = 1; m < 64; m <<= 1) l += __shfl_xor(l, m, 64);
    if (lane == 0) atomicAdd(&accum[0], l);

    const int wgid = tid >> 6;
    float pacc = 0.0f;
    for (int t = 0; t < 32; ++t) {
        const int i = wgid * 32 + t;
        ushort4 ub = reinterpret_cast<const ushort4*>(W + (size_t)i * D)[lane];
        ushort4 vb = reinterpret_cast<const ushort4*>(W + (size_t)(BS + i) * D)[lane];
        pacc += b2f(ub.x) * b2f(vb.x) + b2f(ub.y) * b2f(vb.y)
              + b2f(ub.z) * b2f(vb.z) + b2f(ub.w) * b2f(vb.w);
    }
#pragma unroll
    for (int m = 1; m < 64; m <<= 1) pacc += __shfl_xor(pacc, m, 64);
    if (lane == 0) atomicAdd(&accum[1], INV_T * pacc);

    __syncthreads();                 // block's atomics issued & drained
    if (threadIdx.x == 0) {
        __threadfence();
        int* done = (int*)(accum + 2);
        if (atomicAdd(done, 1) == 31) {          // last of 32 blocks
            float a0 = atomicAdd(&accum[0], 0.0f);   // coherent read
            float a1 = atomicAdd(&accum[1], 0.0f);
            out[0] = a0 * (1.0f / NROW) - a1 * (1.0f / BS);
        }
    }
}

extern "C" void kernel_launch(void* const* d_in, const int* in_sizes, int n_in,
                              void* d_out, int out_size, void* d_ws, size_t ws_size,
                              hipStream_t stream) {
    const float* zi = (const float*)d_in[0];
    const float* zj = (const float*)d_in[1];
    float* out = (float*)d_out;

    unsigned short* W = (unsigned short*)d_ws;                        // 4 MB
    float* rowsum = (float*)((char*)d_ws + (size_t)NROW * D * 2);     // 32 KB
    float* accum  = rowsum + NROW;                                    // 12 B

    k_norm<<<NROW / 4, 256, 0, stream>>>(zi, zj, W, rowsum, accum);
    k_gemm<<<2080, 512, 0, stream>>>(W, rowsum);
    k_finalize<<<32, 256, 0, stream>>>(W, rowsum, accum, out);
}

// Round 12
// 109.534 us; speedup vs baseline: 1.1515x; 1.1515x over previous
//
#include <hip/hip_runtime.h>
#include <hip/hip_bf16.h>

#define BS 4096
#define D 256
#define NROW 8192      // 2*BS
#define INV_T 2.0f
#define BK 32

typedef short short8 __attribute__((ext_vector_type(8)));
typedef float f32x4 __attribute__((ext_vector_type(4)));

__device__ __forceinline__ unsigned short f2b(float x) {
    __hip_bfloat16 h = __float2bfloat16(x);
    return *reinterpret_cast<unsigned short*>(&h);
}
__device__ __forceinline__ float b2f(unsigned short b) {
    unsigned int u = ((unsigned int)b) << 16;
    return __uint_as_float(u);
}

// K1: normalize rows of zi/zj -> bf16 W [8192][256]; zero rowsum + accum(3).
__global__ __launch_bounds__(256) void k_norm(const float* __restrict__ zi,
                                              const float* __restrict__ zj,
                                              unsigned short* __restrict__ W,
                                              float* __restrict__ rowsum,
                                              float* __restrict__ accum) {
    const int gt   = blockIdx.x * 256 + threadIdx.x;
    const int wave = gt >> 6;
    const int lane = threadIdx.x & 63;

    const float* src = (wave < BS) ? (zi + (size_t)wave * D)
                                   : (zj + (size_t)(wave - BS) * D);
    float4 v = reinterpret_cast<const float4*>(src)[lane];
    float ss = v.x * v.x + v.y * v.y + v.z * v.z + v.w * v.w;
#pragma unroll
    for (int m = 1; m < 64; m <<= 1) ss += __shfl_xor(ss, m, 64);
    float inv = rsqrtf(ss);

    ushort4 o;
    o.x = f2b(v.x * inv);
    o.y = f2b(v.y * inv);
    o.z = f2b(v.z * inv);
    o.w = f2b(v.w * inv);
    reinterpret_cast<ushort4*>(W + (size_t)wave * D)[lane] = o;

    if (gt < NROW) rowsum[gt] = 0.0f;
    if (gt < 3)    accum[gt]  = 0.0f;   // [0]=lse, [1]=pos, [2]=done ctr
}

// K2: upper-triangle tiles of G = 2*W@W^T, 128x128 tile.
// r9 geometry (4 waves, 64x64 wave-tiles — LDS-traffic-optimal) + BK=32
// double-buffer at the SAME 32KB LDS footprint. Counted vmcnt: stage(kk+2)
// issued after compute(kk); steady-state wait vmcnt(4) so loads have one full
// compute phase in flight (never drain to 0 mid-loop).
// Swizzle for 64B rows: phys_chunk = log_chunk ^ ((row>>1)&3), applied on the
// pre-swizzled global source AND the ds_read address (both-sides, rule 21).
__global__ __launch_bounds__(256, 4) void k_gemm(const unsigned short* __restrict__ W,
                                                 float* __restrict__ rowsum) {
    __shared__ unsigned short lds[2][2][128 * BK];   // 2 bufs x (A,B) x 8KB = 32KB

    const int tid  = threadIdx.x;
    const int lane = tid & 63;
    const int w    = tid >> 6;      // wave 0..3
    const int wr   = w >> 1;
    const int wc   = w & 1;

    // triangular decode: t -> (bi,bj), 0 <= bi <= bj < 64
    const int t = blockIdx.x;
    const int u = 2079 - t;
    int ri = (int)((sqrtf(8.0f * (float)u + 1.0f) - 1.0f) * 0.5f);
    while ((ri + 1) * (ri + 2) / 2 <= u) ++ri;
    while (ri * (ri + 1) / 2 > u) --ri;
    const int bi = 63 - ri;
    const int bj = 63 - (u - ri * (ri + 1) / 2);
    const int rowBase = bi * 128;
    const int colBase = bj * 128;
    const bool isDiag = (bi == bj);

    f32x4 acc[4][4] = {};

    // staging: per matrix 8 segs of 16 rows (1KB each); wave w -> segs {w, w+4}.
    // lane l: row_in_seg = l>>2, phys chunk = l&3, sources logical chunk
    // (l&3)^((l>>3)&3)  (swizzle involution on the global source)
    const int rowInSeg = lane >> 2;
    const int srcColElems = (((lane & 3) ^ ((lane >> 3) & 3)) * 8);

#define STAGE(p, kk) do {                                                          \
    const int kBase_ = (kk) * BK;                                                  \
    _Pragma("unroll")                                                              \
    for (int c = 0; c < 2; ++c) {                                                  \
        const int seg = c * 4 + w;                                                 \
        const int row = seg * 16 + rowInSeg;                                       \
        const unsigned short* gA = W + (size_t)(rowBase + row) * D + kBase_ + srcColElems; \
        const unsigned short* gB = W + (size_t)(colBase + row) * D + kBase_ + srcColElems; \
        __builtin_amdgcn_global_load_lds(                                          \
            (const __attribute__((address_space(1))) void*)gA,                     \
            (__attribute__((address_space(3))) void*)(&lds[p][0][seg * 512]), 16, 0, 0); \
        __builtin_amdgcn_global_load_lds(                                          \
            (const __attribute__((address_space(1))) void*)gB,                     \
            (__attribute__((address_space(3))) void*)(&lds[p][1][seg * 512]), 16, 0, 0); \
    }                                                                              \
} while (0)

    STAGE(0, 0);   // 4 loads/thread
    STAGE(1, 1);   // 8 outstanding

    for (int kk = 0; kk < 8; ++kk) {
        const int p = kk & 1;
        if (kk < 7) { asm volatile("s_waitcnt vmcnt(4)" ::: "memory"); }
        else        { asm volatile("s_waitcnt vmcnt(0)" ::: "memory"); }
        __builtin_amdgcn_s_barrier();          // all waves' DMA for buf p done
        __builtin_amdgcn_sched_barrier(0);     // keep ds_reads below the barrier

        const unsigned short* pA = &lds[p][0][0];
        const unsigned short* pB = &lds[p][1][0];
        short8 a[4], b[4];
        const int q = lane >> 4;               // logical 8-elem chunk (K slot)
        const int s = (lane >> 1) & 3;         // row-derived swizzle (rows share
                                               // (lane&15) low bits across mi/ni)
        const int ph = (q ^ s) * 8;
#pragma unroll
        for (int mi = 0; mi < 4; ++mi) {
            const int r = wr * 64 + mi * 16 + (lane & 15);
            a[mi] = *reinterpret_cast<const short8*>(pA + r * BK + ph);
        }
#pragma unroll
        for (int ni = 0; ni < 4; ++ni) {
            const int r = wc * 64 + ni * 16 + (lane & 15);
            b[ni] = *reinterpret_cast<const short8*>(pB + r * BK + ph);
        }
#pragma unroll
        for (int mi = 0; mi < 4; ++mi)
#pragma unroll
            for (int ni = 0; ni < 4; ++ni)
                acc[mi][ni] = __builtin_amdgcn_mfma_f32_16x16x32_bf16(
                    a[mi], b[ni], acc[mi][ni], 0, 0, 0);

        __builtin_amdgcn_s_barrier();          // all waves done reading buf p
        if (kk < 6) STAGE(p, kk + 2);          // refill freed buffer (+4 loads)
    }
#undef STAGE

    // Epilogue. C/D layout (16x16x32): col = lane&15, row = (lane>>4)*4 + reg.
    float colacc[4] = {0.f, 0.f, 0.f, 0.f};
#pragma unroll
    for (int mi = 0; mi < 4; ++mi) {
#pragma unroll
        for (int j = 0; j < 4; ++j) {
            const int gr = rowBase + wr * 64 + mi * 16 + (lane >> 4) * 4 + j;
            float s2 = 0.0f;
#pragma unroll
            for (int ni = 0; ni < 4; ++ni) {
                float e;
                if (isDiag) {
                    const int gc = colBase + wc * 64 + ni * 16 + (lane & 15);
                    e = (gr == gc) ? 0.0f : __expf(acc[mi][ni][j] * INV_T);
                } else {
                    e = __expf(acc[mi][ni][j] * INV_T);
                }
                s2 += e;
                colacc[ni] += e;
            }
            s2 += __shfl_xor(s2, 1, 64);
            s2 += __shfl_xor(s2, 2, 64);
            s2 += __shfl_xor(s2, 4, 64);
            s2 += __shfl_xor(s2, 8, 64);
            if ((lane & 15) == 0) atomicAdd(&rowsum[gr], s2);
        }
    }
    if (!isDiag) {   // symmetric contribution: this tile is also tile (bj,bi)
#pragma unroll
        for (int ni = 0; ni < 4; ++ni) {
            float cs = colacc[ni];
            cs += __shfl_xor(cs, 16, 64);
            cs += __shfl_xor(cs, 32, 64);
            if ((lane >> 4) == 0)
                atomicAdd(&rowsum[colBase + wc * 64 + ni * 16 + lane], cs);
        }
    }
}

// K3: lse_sum = sum(log(rowsum)); pos_sum = sum_i 2*dot(u_i,v_i);
// last finished block writes the final loss.
__global__ __launch_bounds__(256) void k_finalize(const unsigned short* __restrict__ W,
                                                  const float* __restrict__ rowsum,
                                                  float* __restrict__ accum,
                                                  float* __restrict__ out) {
    const int tid  = blockIdx.x * 256 + threadIdx.x;  // 32 blocks -> 8192 threads
    const int lane = threadIdx.x & 63;

    float l = logf(rowsum[tid]);
#pragma unroll
    for (int m = 1; m < 64; m <<= 1) l += __shfl_xor(l, m, 64);
    if (lane == 0) atomicAdd(&accum[0], l);

    const int wgid = tid >> 6;
    float pacc = 0.0f;
    for (int t = 0; t < 32; ++t) {
        const int i = wgid * 32 + t;
        ushort4 ub = reinterpret_cast<const ushort4*>(W + (size_t)i * D)[lane];
        ushort4 vb = reinterpret_cast<const ushort4*>(W + (size_t)(BS + i) * D)[lane];
        pacc += b2f(ub.x) * b2f(vb.x) + b2f(ub.y) * b2f(vb.y)
              + b2f(ub.z) * b2f(vb.z) + b2f(ub.w) * b2f(vb.w);
    }
#pragma unroll
    for (int m = 1; m < 64; m <<= 1) pacc += __shfl_xor(pacc, m, 64);
    if (lane == 0) atomicAdd(&accum[1], INV_T * pacc);

    __syncthreads();                 // block's atomics issued & drained
    if (threadIdx.x == 0) {
        __threadfence();
        int* done = (int*)(accum + 2);
        if (atomicAdd(done, 1) == 31) {          // last of 32 blocks
            float a0 = atomicAdd(&accum[0], 0.0f);   // coherent read
            float a1 = atomicAdd(&accum[1], 0.0f);
            out[0] = a0 * (1.0f / NROW) - a1 * (1.0f / BS);
        }
    }
}

extern "C" void kernel_launch(void* const* d_in, const int* in_sizes, int n_in,
                              void* d_out, int out_size, void* d_ws, size_t ws_size,
                              hipStream_t stream) {
    const float* zi = (const float*)d_in[0];
    const float* zj = (const float*)d_in[1];
    float* out = (float*)d_out;

    unsigned short* W = (unsigned short*)d_ws;                        // 4 MB
    float* rowsum = (float*)((char*)d_ws + (size_t)NROW * D * 2);     // 32 KB
    float* accum  = rowsum + NROW;                                    // 12 B

    k_norm<<<NROW / 4, 256, 0, stream>>>(zi, zj, W, rowsum, accum);
    k_gemm<<<2080, 256, 0, stream>>>(W, rowsum);
    k_finalize<<<32, 256, 0, stream>>>(W, rowsum, accum, out);
}